// Round 1
// baseline (2771.822 us; speedup 1.0000x reference)
//
#include <hip/hip_runtime.h>
#include <hip/hip_bf16.h>

#define IGNORE_INDEX (-100)
#define BETA 0.1f

typedef __bf16 bf16x8 __attribute__((ext_vector_type(8)));
typedef float  f32x4  __attribute__((ext_vector_type(4)));

__device__ __forceinline__ void gload_lds16(const void* g, void* l) {
  __builtin_amdgcn_global_load_lds((const __attribute__((address_space(1))) void*)g,
                                   (__attribute__((address_space(3))) void*)l, 16, 0, 0);
}

__device__ __forceinline__ unsigned short f2bf(float f) {
  __hip_bfloat16 h = __float2bfloat16(f);
  return __builtin_bit_cast(unsigned short, h);
}

// ---------------- cast fp32 -> bf16, 8 elems/thread ----------------
__global__ void cast_f32_bf16_k(const float* __restrict__ src,
                                unsigned short* __restrict__ dst, long long n) {
  long long i = (long long)blockIdx.x * blockDim.x + threadIdx.x;
  long long b = i * 8;
  if (b + 8 > n) return;
  const float4* s4 = (const float4*)(src + b);
  float4 a = s4[0], c = s4[1];
  uint4 o;
  o.x = (unsigned)f2bf(a.x) | ((unsigned)f2bf(a.y) << 16);
  o.y = (unsigned)f2bf(a.z) | ((unsigned)f2bf(a.w) << 16);
  o.z = (unsigned)f2bf(c.x) | ((unsigned)f2bf(c.y) << 16);
  o.w = (unsigned)f2bf(c.z) | ((unsigned)f2bf(c.w) << 16);
  *(uint4*)(dst + b) = o;
}

// ---------------- fused GEMM (128x128 tile) + per-vtile logsumexp partials ----
// A: bf16 [4096][2048] tokens, B: bf16 [32000][2048] vocab rows (NT GEMM)
// partials: [4096][250] float2 {max, sumexp} for this path
// label_logit: [4096] floats for this path
__global__ __launch_bounds__(256) void gemm_lse(
    const unsigned short* __restrict__ A,
    const unsigned short* __restrict__ B,
    const int* __restrict__ labels,
    float2* __restrict__ partials,
    float* __restrict__ label_logit) {
  // swizzle: 32 consecutive blocks share one W tile (m fastest), groups of 10 vtiles
  int bid = blockIdx.x;
  int group = bid / 320;
  int within = bid - group * 320;
  int mtile = within & 31;
  int vtile = group * 10 + (within >> 5);

  const int tid = threadIdx.x;
  const int lane = tid & 63;
  const int wave = tid >> 6;
  const int wy = wave >> 1, wx = wave & 1;   // 2x2 wave grid, each wave 64x64
  const int quad = lane >> 4;
  const int r16 = lane & 15;

  __shared__ alignas(16) unsigned short As[128 * 32];
  __shared__ alignas(16) unsigned short Bs[128 * 32];
  __shared__ int lbl[128];
  __shared__ float redM[2][128];
  __shared__ float redS[2][128];

  const int m0 = mtile * 128;
  const int n0 = vtile * 128;

  if (tid < 128) lbl[tid] = labels[m0 + tid];

  // staging addressing: thread tid covers rows {tid>>2, (tid>>2)+64}, k-chunk (tid&3)*8
  const int row0 = tid >> 2;
  const int kc0 = (tid & 3) * 8;
  const unsigned short* Ag = A + (size_t)(m0 + row0) * 2048 + kc0;
  const unsigned short* Bg = B + (size_t)(n0 + row0) * 2048 + kc0;
  unsigned short* As0 = &As[tid * 8];
  unsigned short* As1 = &As[(256 + tid) * 8];
  unsigned short* Bs0 = &Bs[tid * 8];
  unsigned short* Bs1 = &Bs[(256 + tid) * 8];

  f32x4 acc[4][4] = {};

  for (int k0 = 0; k0 < 2048; k0 += 32) {
    __syncthreads();
    gload_lds16(Ag + k0, As0);
    gload_lds16(Ag + (size_t)64 * 2048 + k0, As1);
    gload_lds16(Bg + k0, Bs0);
    gload_lds16(Bg + (size_t)64 * 2048 + k0, Bs1);
    __syncthreads();

    bf16x8 af[4], bfr[4];
#pragma unroll
    for (int mt = 0; mt < 4; mt++)
      af[mt] = *(const bf16x8*)&As[(wy * 64 + mt * 16 + r16) * 32 + quad * 8];
#pragma unroll
    for (int nt = 0; nt < 4; nt++)
      bfr[nt] = *(const bf16x8*)&Bs[(wx * 64 + nt * 16 + r16) * 32 + quad * 8];
#pragma unroll
    for (int mt = 0; mt < 4; mt++)
#pragma unroll
      for (int nt = 0; nt < 4; nt++)
        acc[mt][nt] = __builtin_amdgcn_mfma_f32_16x16x32_bf16(af[mt], bfr[nt], acc[mt][nt], 0, 0, 0);
  }

  // ---- epilogue: label logit pick-off ----
  // C/D layout: col = r16, row = quad*4 + reg   (m89/m91 verified)
#pragma unroll
  for (int mt = 0; mt < 4; mt++) {
#pragma unroll
    for (int e = 0; e < 4; e++) {
      int ml = wy * 64 + mt * 16 + quad * 4 + e;
      int lb = lbl[ml];
#pragma unroll
      for (int nt = 0; nt < 4; nt++) {
        int ng = n0 + wx * 64 + nt * 16 + r16;
        if (lb == ng) label_logit[m0 + ml] = acc[mt][nt][e];
      }
    }
  }

  // ---- per-row max/sumexp over this wave's 64 cols ----
#pragma unroll
  for (int mt = 0; mt < 4; mt++) {
#pragma unroll
    for (int e = 0; e < 4; e++) {
      float v0 = acc[mt][0][e], v1 = acc[mt][1][e], v2 = acc[mt][2][e], v3 = acc[mt][3][e];
      float mx = fmaxf(fmaxf(v0, v1), fmaxf(v2, v3));
#pragma unroll
      for (int d = 1; d < 16; d <<= 1) mx = fmaxf(mx, __shfl_xor(mx, d));
      float s = expf(v0 - mx) + expf(v1 - mx) + expf(v2 - mx) + expf(v3 - mx);
#pragma unroll
      for (int d = 1; d < 16; d <<= 1) s += __shfl_xor(s, d);
      if (r16 == 0) {
        int ml = wy * 64 + mt * 16 + quad * 4 + e;
        redM[wx][ml] = mx;
        redS[wx][ml] = s;
      }
    }
  }
  __syncthreads();
  if (tid < 128) {
    float ma = redM[0][tid], mb = redM[1][tid];
    float M = fmaxf(ma, mb);
    float S = redS[0][tid] * expf(ma - M) + redS[1][tid] * expf(mb - M);
    partials[(size_t)(m0 + tid) * 250 + vtile] = make_float2(M, S);
  }
}

// ---------------- combine partials -> per-batch mean logp ----------------
// grid 16: blockIdx.x = path*8 + batch
__global__ void reduce_lp(const float2* __restrict__ partials,   // [2][4096][250]
                          const float* __restrict__ label_logit, // [2][4096]
                          const int* __restrict__ labels,        // [4096]
                          float* __restrict__ batch_lp) {        // [2][8]
  int path = blockIdx.x >> 3;
  int batch = blockIdx.x & 7;
  int lane = threadIdx.x & 63;
  int wave = threadIdx.x >> 6;
  const float2* P = partials + ((size_t)path * 4096 + batch * 512) * 250;
  const float* LL = label_logit + (size_t)path * 4096 + batch * 512;
  const int* Y = labels + batch * 512;
  __shared__ float wsum[4];
  __shared__ int wcnt[4];
  float sum = 0.f;
  int cnt = 0;
  for (int t = wave; t < 512; t += 4) {
    float m = -1e30f, s = 0.f;
    for (int j = lane; j < 250; j += 64) {
      float2 p = P[(size_t)t * 250 + j];
      if (p.x > m) { s = s * expf(m - p.x) + p.y; m = p.x; }
      else          s += p.y * expf(p.x - m);
    }
#pragma unroll
    for (int d = 1; d < 64; d <<= 1) {
      float om = __shfl_xor(m, d);
      float os = __shfl_xor(s, d);
      float M = fmaxf(m, om);
      s = s * expf(m - M) + os * expf(om - M);
      m = M;
    }
    float lse = m + logf(s);
    int lab = Y[t];
    if (lab != IGNORE_INDEX) { sum += LL[t] - lse; cnt++; }
  }
  if (lane == 0) { wsum[wave] = sum; wcnt[wave] = cnt; }
  __syncthreads();
  if (threadIdx.x == 0) {
    float S = 0.f;
    int C = 0;
    for (int w = 0; w < 4; w++) { S += wsum[w]; C += wcnt[w]; }
    batch_lp[blockIdx.x] = C ? S / (float)C : 0.f;
  }
}

// ---------------- final KTO loss ----------------
__global__ void final_loss(const float* __restrict__ batch_lp, float* __restrict__ out) {
  if (threadIdx.x == 0 && blockIdx.x == 0) {
    float tot = 0.f;
    for (int b = 0; b < 8; b++) {
      float d = batch_lp[b] - batch_lp[8 + b];   // policy - ref
      float z = (b < 4) ? (BETA * d) : (-BETA * d);
      float sg = 1.f / (1.f + expf(-z));
      tot += 1.f - sg;
    }
    out[0] = tot / 8.f;
  }
}

extern "C" void kernel_launch(void* const* d_in, const int* in_sizes, int n_in,
                              void* d_out, int out_size, void* d_ws, size_t ws_size,
                              hipStream_t stream) {
  const float* x     = (const float*)d_in[0];
  const float* ref_x = (const float*)d_in[1];
  const int*   y     = (const int*)d_in[2];
  const float* W     = (const float*)d_in[3];
  const float* ref_W = (const float*)d_in[4];

  // workspace layout (~181 MB):
  //   xb  bf16 4096*2048, rxb bf16 4096*2048, Wb bf16 32000*2048 (reused per path),
  //   partials float2 [2][4096][250], label_logit [2][4096], batch_lp [2][8]
  unsigned short* xb  = (unsigned short*)d_ws;
  unsigned short* rxb = xb + (size_t)8388608;
  unsigned short* Wb  = rxb + (size_t)8388608;
  char* p2 = (char*)(Wb + (size_t)65536000);
  float2* parts = (float2*)p2;
  float* lablog = (float*)(p2 + (size_t)2 * 4096 * 250 * sizeof(float2));
  float* blp = lablog + 2 * 4096;

  cast_f32_bf16_k<<<4096, 256, 0, stream>>>(x, xb, 8388608LL);
  cast_f32_bf16_k<<<4096, 256, 0, stream>>>(ref_x, rxb, 8388608LL);

  // path 0: policy
  cast_f32_bf16_k<<<32000, 256, 0, stream>>>(W, Wb, 65536000LL);
  gemm_lse<<<8000, 256, 0, stream>>>(xb, Wb, y, parts, lablog);

  // path 1: reference (reuse Wb; stream order serializes)
  cast_f32_bf16_k<<<32000, 256, 0, stream>>>(ref_W, Wb, 65536000LL);
  gemm_lse<<<8000, 256, 0, stream>>>(rxb, Wb, y, parts + (size_t)4096 * 250, lablog + 4096);

  reduce_lp<<<16, 256, 0, stream>>>(parts, lablog, y, blp);
  final_loss<<<1, 64, 0, stream>>>(blp, (float*)d_out);
}